// Round 13
// baseline (161.956 us; speedup 1.0000x reference)
//
#include <hip/hip_runtime.h>

typedef __bf16 bf16_t;
typedef float  f32x4  __attribute__((ext_vector_type(4)));
typedef long   longx2 __attribute__((ext_vector_type(2)));
typedef unsigned char u8;
typedef unsigned long long u64;

#define B_DIM 4
#define S_DIM 4096
#define D_DIM 1024
#define M_DIM (B_DIM * S_DIM)   // 16384 rows

#define CHUNK 32   // scan output steps per block
#define WARM  16   // scan warm-up steps

// pi-permutation within each 64-byte K-chunk: logical k = 64c+32h+8u+b
// stored at pos = 64c+16u+8h+b  (16B unit u = lane-group u's {kk0,kk1} pair)
__device__ __forceinline__ int pperm(int k) {
  return (k & ~63) | (((k >> 3) & 3) << 4) | (((k >> 5) & 1) << 3) | (k & 7);
}

__device__ __forceinline__ void g2l16(const void* g, void* l) {
  __builtin_amdgcn_global_load_lds(
      (const __attribute__((address_space(1))) void*)g,
      (__attribute__((address_space(3))) void*)l, 16, 0, 0);
}

// -------- LayerNorm fp32 -> fp8 e4m3 (pi-permuted rows), wave per row -----
__global__ __launch_bounds__(64) void ln_kernel(
    const float* __restrict__ x, const float* __restrict__ gamma,
    const float* __restrict__ beta, u8* __restrict__ h) {
  const int row  = blockIdx.x;
  const int lane = threadIdx.x;
  const float4* xr = (const float4*)(x + (size_t)row * D_DIM);
  float4 v[4];
  float s = 0.f, s2 = 0.f;
#pragma unroll
  for (int j = 0; j < 4; ++j) {
    v[j] = xr[j * 64 + lane];
    s += v[j].x + v[j].y + v[j].z + v[j].w;
    s2 = fmaf(v[j].x, v[j].x, s2);
    s2 = fmaf(v[j].y, v[j].y, s2);
    s2 = fmaf(v[j].z, v[j].z, s2);
    s2 = fmaf(v[j].w, v[j].w, s2);
  }
#pragma unroll
  for (int off = 32; off; off >>= 1) {
    s  += __shfl_xor(s, off);
    s2 += __shfl_xor(s2, off);
  }
  const float mu  = s * (1.f / (float)D_DIM);
  const float var = fmaf(-mu, mu, s2 * (1.f / (float)D_DIM));
  const float inv = rsqrtf(var + 1e-5f);
  int* hr = (int*)(h + (size_t)row * D_DIM);
#pragma unroll
  for (int j = 0; j < 4; ++j) {
    const float4 g4 = ((const float4*)gamma)[j * 64 + lane];
    const float4 b4 = ((const float4*)beta)[j * 64 + lane];
    const float o0 = fmaf((v[j].x - mu) * inv, g4.x, b4.x);
    const float o1 = fmaf((v[j].y - mu) * inv, g4.y, b4.y);
    const float o2 = fmaf((v[j].z - mu) * inv, g4.z, b4.z);
    const float o3 = fmaf((v[j].w - mu) * inv, g4.w, b4.w);
    int p = __builtin_amdgcn_cvt_pk_fp8_f32(o0, o1, 0, false);
    p = __builtin_amdgcn_cvt_pk_fp8_f32(o2, o3, p, true);
    hr[pperm(j * 256 + lane * 4) >> 2] = p;
  }
}

// ---- W [K][N] fp32 -> WT [N][K] fp8 e4m3, x16 pre-scale, pi-permuted -----
__global__ __launch_bounds__(256) void transpose_fp8_kernel(
    const float* __restrict__ W, u8* __restrict__ WT) {
  __shared__ float tile[32][33];
  const int tx = threadIdx.x & 31;
  const int ty = threadIdx.x >> 5;
  const int bn = blockIdx.x * 32;
  const int bk = blockIdx.y * 32;
#pragma unroll
  for (int i = 0; i < 32; i += 8)
    tile[ty + i][tx] = W[(size_t)(bk + ty + i) * D_DIM + bn + tx];
  __syncthreads();
#pragma unroll
  for (int i = 0; i < 32; i += 8) {
    const int p =
        __builtin_amdgcn_cvt_pk_fp8_f32(16.f * tile[tx][ty + i], 0.f, 0, false);
    WT[(size_t)(bn + ty + i) * D_DIM + pperm(bk + tx)] = (u8)(p & 0xff);
  }
}

// === fp8 NT GEMM: A via LDS ring-3, B DIRECT global->reg (L2-resident) ====
// MODE 0 (GEMM1): h8 x (16*W_in)  -> c8 = fp8(acc/16 + bias)  [linear]
// MODE 1 (GEMM2): (16*y8) x (16*W_out) -> f32 out = xres + acc/256 + bias
// 128x256 tile, 8 waves (wave 64x64). A LDS slot = 8KB [128 rows][64B],
// stored unit u at phys unit u^((row>>1)&3) [measured 0-conflict].
// ORDERING NOTE: GLB carries a "memory" clobber so the g2l16 builtin cannot
// be reordered across it (R12 NaN root cause: vmcnt queue order scrambled).
#define NTK 16        // K / 64

#define VMCNT(n) asm volatile("s_waitcnt vmcnt(" #n ")" ::: "memory")
#define DSRX(d, a, off) \
  asm volatile("ds_read_b128 %0, %1 offset:" #off : "=v"(d) : "v"(a))
#define GLB(d, a) \
  asm volatile("global_load_dwordx4 %0, %1, off" : "=v"(d) : "v"(a) : "memory")

template <int MODE>
__global__ __launch_bounds__(512, 4) void gemm_fp8_kernel(
    const u8* __restrict__ A, const u8* __restrict__ BT,
    const float* __restrict__ bias, const float* __restrict__ xres,
    void* __restrict__ Cout) {
  __shared__ __attribute__((aligned(16))) char lds[3][8192];
  const int tid  = threadIdx.x;
  const int lane = tid & 63;
  const int wave = tid >> 6;           // 0..7
  const int wr = wave >> 2;            // 0..1 (M half: 64 rows)
  const int wc = wave & 3;             // 0..3 (N quarter: 64 cols)
  const int bid = blockIdx.x;
  const int swz = (bid & 7) * 64 + (bid >> 3);   // 512 blocks, 8 XCDs
  const int m0 = (swz >> 2) * 128;     // 128 m-panels
  const int n0 = (swz & 3) * 256;      // 4 n-panels

  // staging (A only): thread covers (row = tid>>2, phys unit = tid&3)
  const int us = (((tid & 3) ^ ((tid >> 3) & 3)) << 4);
  const u8* srcA = A + (size_t)(m0 + (tid >> 2)) * D_DIM + us;
  const int l16 = tid * 16;

  // A fragment read base: group g = lane>>4 at phys unit g^((lane>>1)&3)
  const uint32_t lbase = (uint32_t)(uintptr_t)&lds[0][0];
  const int sw = (((lane >> 4) ^ ((lane >> 1) & 3)) << 4);
  const uint32_t aoff = lbase + (uint32_t)((wr * 64 + (lane & 15)) * 64 + sw);

  // B fragment global base: row = n0 + wc*64 + n*16 + (lane&15), unit lane>>4
  const u8* bp = BT + (size_t)(n0 + wc * 64 + (lane & 15)) * D_DIM +
                 ((lane >> 4) << 4);

  f32x4 acc[4][4];
#pragma unroll
  for (int m = 0; m < 4; ++m)
#pragma unroll
    for (int n = 0; n < 4; ++n) acc[m][n] = (f32x4){0.f, 0.f, 0.f, 0.f};

#define STAGEA(T, SLOT) \
  g2l16(srcA + (size_t)(T) * 64, (char*)lds + (SLOT) * 8192 + l16)

#define LOADB(BF, T)                                        \
  {                                                         \
    const u64 a_ = (u64)(uintptr_t)(bp + (size_t)(T) * 64); \
    GLB(BF[0], a_);                                         \
    GLB(BF[1], a_ + 16384u);                                \
    GLB(BF[2], a_ + 32768u);                                \
    GLB(BF[3], a_ + 49152u);                                \
  }

#define ITER(T, BCUR, BNXT)                                            \
  {                                                                    \
    if ((T) < NTK - 1) { VMCNT(1); } else { VMCNT(0); }                \
    __builtin_amdgcn_s_barrier();                                      \
    asm volatile("" ::: "memory");                                     \
    if ((T) + 1 < NTK) LOADB(BNXT, (T) + 1);                           \
    if ((T) + 2 < NTK) STAGEA((T) + 2, ((T) + 2) % 3);                 \
    __builtin_amdgcn_sched_barrier(0);                                 \
    longx2 af[4];                                                      \
    const uint32_t aA = aoff + (uint32_t)(((T) % 3) * 8192);           \
    DSRX(af[0], aA, 0);                                                \
    DSRX(af[1], aA, 1024);                                             \
    DSRX(af[2], aA, 2048);                                             \
    DSRX(af[3], aA, 3072);                                             \
    asm volatile("s_waitcnt lgkmcnt(0)" ::: "memory");                 \
    __builtin_amdgcn_sched_barrier(0);                                 \
    _Pragma("unroll") for (int m = 0; m < 4; ++m)                      \
        _Pragma("unroll") for (int n = 0; n < 4; ++n)                  \
            acc[m][n] = __builtin_amdgcn_mfma_f32_16x16x32_fp8_fp8(    \
                af[m][0], BCUR[n][0], acc[m][n], 0, 0, 0);             \
    _Pragma("unroll") for (int m = 0; m < 4; ++m)                      \
        _Pragma("unroll") for (int n = 0; n < 4; ++n)                  \
            acc[m][n] = __builtin_amdgcn_mfma_f32_16x16x32_fp8_fp8(    \
                af[m][1], BCUR[n][1], acc[m][n], 0, 0, 0);             \
  }

  longx2 bf_e[4], bf_o[4];
  // prologue: pending queue = [A0, B0x4, A1]  (order pinned by mem clobbers)
  STAGEA(0, 0);
  LOADB(bf_e, 0);
  STAGEA(1, 1);

#pragma unroll
  for (int t2 = 0; t2 < NTK; t2 += 2) {
    ITER(t2, bf_e, bf_o);
    ITER(t2 + 1, bf_o, bf_e);
  }

#undef ITER
#undef LOADB
#undef STAGEA

  // epilogue: C/D layout col = lane&15, row = (lane>>4)*4 + r
  const int rbase = m0 + wr * 64 + ((lane >> 4) << 2);
  const int cbase = n0 + wc * 64 + (lane & 15);
#pragma unroll
  for (int n = 0; n < 4; ++n) {
    const int col = cbase + n * 16;
    const float bn = bias[col];
#pragma unroll
    for (int m = 0; m < 4; ++m) {
      const int row = rbase + m * 16;
#pragma unroll
      for (int r = 0; r < 4; ++r) {
        const size_t idx = (size_t)(row + r) * D_DIM + col;
        if (MODE == 0) {
          const float cv = fmaf(acc[m][n][r], 0.0625f, bn);
          const int p = __builtin_amdgcn_cvt_pk_fp8_f32(cv, 0.f, 0, false);
          ((u8*)Cout)[idx] = (u8)(p & 0xff);
        } else {
          ((float*)Cout)[idx] =
              xres[idx] + fmaf(acc[m][n][r], 1.f / 256.f, bn);
        }
      }
    }
  }
}

// --- chunked chaotic scan: c fp8 linear in, y fp8 x16 pi-permuted out -----
__global__ __launch_bounds__(64) void scan_kernel(
    const u8* __restrict__ c, u8* __restrict__ y) {
  const int b     = blockIdx.y;
  const int chunk = blockIdx.x;
  const int t0    = chunk * CHUNK;
  const int start = (chunk == 0) ? 0 : t0 - WARM;
  const int tend  = t0 + CHUNK;
  const int lane  = threadIdx.x;

  float zre[8], zim[8];
#pragma unroll
  for (int j = 0; j < 8; ++j) { zre[j] = 0.f; zim[j] = 0.f; }

  const int dre = lane * 8;
  const int pre = (dre & ~63) | (((dre >> 3) & 3) << 4) | (((dre >> 5) & 1) << 3);
  const int pim = 512 + pre;

  const u8* crow = c + ((size_t)b * S_DIM + start) * D_DIM;
  u64 cr = *(const u64*)(crow + lane * 8);
  u64 ci = *(const u64*)(crow + 512 + lane * 8);

  for (int t = start; t < tend; ++t) {
    u64 crn = cr, cin = ci;
    if (t + 1 < tend) {
      const u8* nrow = c + ((size_t)b * S_DIM + (t + 1)) * D_DIM;
      crn = *(const u64*)(nrow + lane * 8);
      cin = *(const u64*)(nrow + 512 + lane * 8);
    }
    float cre[8], cim[8];
    {
      const unsigned rl = (unsigned)cr, rh = (unsigned)(cr >> 32);
      const unsigned il = (unsigned)ci, ih = (unsigned)(ci >> 32);
      cre[0] = __builtin_amdgcn_cvt_f32_fp8(rl, 0);
      cre[1] = __builtin_amdgcn_cvt_f32_fp8(rl, 1);
      cre[2] = __builtin_amdgcn_cvt_f32_fp8(rl, 2);
      cre[3] = __builtin_amdgcn_cvt_f32_fp8(rl, 3);
      cre[4] = __builtin_amdgcn_cvt_f32_fp8(rh, 0);
      cre[5] = __builtin_amdgcn_cvt_f32_fp8(rh, 1);
      cre[6] = __builtin_amdgcn_cvt_f32_fp8(rh, 2);
      cre[7] = __builtin_amdgcn_cvt_f32_fp8(rh, 3);
      cim[0] = __builtin_amdgcn_cvt_f32_fp8(il, 0);
      cim[1] = __builtin_amdgcn_cvt_f32_fp8(il, 1);
      cim[2] = __builtin_amdgcn_cvt_f32_fp8(il, 2);
      cim[3] = __builtin_amdgcn_cvt_f32_fp8(il, 3);
      cim[4] = __builtin_amdgcn_cvt_f32_fp8(ih, 0);
      cim[5] = __builtin_amdgcn_cvt_f32_fp8(ih, 1);
      cim[6] = __builtin_amdgcn_cvt_f32_fp8(ih, 2);
      cim[7] = __builtin_amdgcn_cvt_f32_fp8(ih, 3);
    }
    float nr[8], ni[8];
    float ss = 0.f;
#pragma unroll
    for (int j = 0; j < 8; ++j) {
      const float a  = zre[j], bb = zim[j];
      const float rr = fmaf(a, a, fmaf(-bb, bb, cre[j]));
      const float ii = fmaf(2.f * a, bb, cim[j]);
      nr[j] = rr; ni[j] = ii;
      ss = fmaf(rr, rr, ss);
      ss = fmaf(ii, ii, ss);
    }
#pragma unroll
    for (int off = 32; off; off >>= 1) ss += __shfl_xor(ss, off);
    const float nrm = sqrtf(ss + 1e-12f);
    const float sc  = 2.0f / fmaxf(nrm, 2.0f);
#pragma unroll
    for (int j = 0; j < 8; ++j) { zre[j] = nr[j] * sc; zim[j] = ni[j] * sc; }
    if (t >= t0) {
      u8* yrow = y + ((size_t)b * S_DIM + t) * D_DIM;
      int pr0 = __builtin_amdgcn_cvt_pk_fp8_f32(16.f * zre[0], 16.f * zre[1], 0, false);
      pr0 = __builtin_amdgcn_cvt_pk_fp8_f32(16.f * zre[2], 16.f * zre[3], pr0, true);
      int pr1 = __builtin_amdgcn_cvt_pk_fp8_f32(16.f * zre[4], 16.f * zre[5], 0, false);
      pr1 = __builtin_amdgcn_cvt_pk_fp8_f32(16.f * zre[6], 16.f * zre[7], pr1, true);
      int pi0 = __builtin_amdgcn_cvt_pk_fp8_f32(16.f * zim[0], 16.f * zim[1], 0, false);
      pi0 = __builtin_amdgcn_cvt_pk_fp8_f32(16.f * zim[2], 16.f * zim[3], pi0, true);
      int pi1 = __builtin_amdgcn_cvt_pk_fp8_f32(16.f * zim[4], 16.f * zim[5], 0, false);
      pi1 = __builtin_amdgcn_cvt_pk_fp8_f32(16.f * zim[6], 16.f * zim[7], pi1, true);
      *(u64*)(yrow + pre) = ((u64)(unsigned)pr1 << 32) | (unsigned)pr0;
      *(u64*)(yrow + pim) = ((u64)(unsigned)pi1 << 32) | (unsigned)pi0;
    }
    cr = crn; ci = cin;
  }
}

extern "C" void kernel_launch(void* const* d_in, const int* in_sizes, int n_in,
                              void* d_out, int out_size, void* d_ws, size_t ws_size,
                              hipStream_t stream) {
  const float* x     = (const float*)d_in[0];
  const float* gamma = (const float*)d_in[1];
  const float* beta  = (const float*)d_in[2];
  const float* W_in  = (const float*)d_in[3];
  const float* b_in  = (const float*)d_in[4];
  const float* W_out = (const float*)d_in[5];
  const float* b_out = (const float*)d_in[6];
  float* out = (float*)d_out;

  char* ws = (char*)d_ws;
  u8* hy8  = (u8*)(ws);                  // 16 MiB: h fp8, then y fp8 (alias)
  u8* c8   = (u8*)(ws + (16ull << 20));  // 16 MiB: c fp8 (linear)
  u8* wti8 = (u8*)(ws + (64ull << 20));  // 1 MiB:  W_in^T  fp8 (x16, perm)
  u8* wto8 = (u8*)(ws + (65ull << 20));  // 1 MiB:  W_out^T fp8 (x16, perm)

  transpose_fp8_kernel<<<dim3(32, 32), 256, 0, stream>>>(W_in, wti8);
  transpose_fp8_kernel<<<dim3(32, 32), 256, 0, stream>>>(W_out, wto8);
  ln_kernel<<<M_DIM, 64, 0, stream>>>(x, gamma, beta, hy8);
  gemm_fp8_kernel<0><<<512, 512, 0, stream>>>(hy8, wti8, b_in, nullptr, c8);
  scan_kernel<<<dim3(S_DIM / CHUNK, B_DIM), 64, 0, stream>>>(c8, hy8);
  gemm_fp8_kernel<1><<<512, 512, 0, stream>>>(hy8, wto8, b_out, x, out);
}

// Round 14
// 124.895 us; speedup vs baseline: 1.2967x; 1.2967x over previous
//
#include <hip/hip_runtime.h>

typedef __bf16 bf16_t;
typedef float  f32x4  __attribute__((ext_vector_type(4)));
typedef long   longx2 __attribute__((ext_vector_type(2)));
typedef unsigned char u8;
typedef unsigned long long u64;

#define B_DIM 4
#define S_DIM 4096
#define D_DIM 1024
#define M_DIM (B_DIM * S_DIM)   // 16384 rows

#define CHUNK 32   // scan output steps per block
#define WARM  16   // scan warm-up steps

// pi-permutation within each 64-byte K-chunk: logical k = 64c+32h+8u+b
// stored at pos = 64c+16u+8h+b  (16B unit u = lane-group u's {kk0,kk1} pair)
__device__ __forceinline__ int pperm(int k) {
  return (k & ~63) | (((k >> 3) & 3) << 4) | (((k >> 5) & 1) << 3) | (k & 7);
}

__device__ __forceinline__ void g2l16(const void* g, void* l) {
  __builtin_amdgcn_global_load_lds(
      (const __attribute__((address_space(1))) void*)g,
      (__attribute__((address_space(3))) void*)l, 16, 0, 0);
}

// -------- LayerNorm fp32 -> fp8 e4m3 (pi-permuted rows), wave per row -----
__global__ __launch_bounds__(64) void ln_kernel(
    const float* __restrict__ x, const float* __restrict__ gamma,
    const float* __restrict__ beta, u8* __restrict__ h) {
  const int row  = blockIdx.x;
  const int lane = threadIdx.x;
  const float4* xr = (const float4*)(x + (size_t)row * D_DIM);
  float4 v[4];
  float s = 0.f, s2 = 0.f;
#pragma unroll
  for (int j = 0; j < 4; ++j) {
    v[j] = xr[j * 64 + lane];
    s += v[j].x + v[j].y + v[j].z + v[j].w;
    s2 = fmaf(v[j].x, v[j].x, s2);
    s2 = fmaf(v[j].y, v[j].y, s2);
    s2 = fmaf(v[j].z, v[j].z, s2);
    s2 = fmaf(v[j].w, v[j].w, s2);
  }
#pragma unroll
  for (int off = 32; off; off >>= 1) {
    s  += __shfl_xor(s, off);
    s2 += __shfl_xor(s2, off);
  }
  const float mu  = s * (1.f / (float)D_DIM);
  const float var = fmaf(-mu, mu, s2 * (1.f / (float)D_DIM));
  const float inv = rsqrtf(var + 1e-5f);
  int* hr = (int*)(h + (size_t)row * D_DIM);
#pragma unroll
  for (int j = 0; j < 4; ++j) {
    const float4 g4 = ((const float4*)gamma)[j * 64 + lane];
    const float4 b4 = ((const float4*)beta)[j * 64 + lane];
    const float o0 = fmaf((v[j].x - mu) * inv, g4.x, b4.x);
    const float o1 = fmaf((v[j].y - mu) * inv, g4.y, b4.y);
    const float o2 = fmaf((v[j].z - mu) * inv, g4.z, b4.z);
    const float o3 = fmaf((v[j].w - mu) * inv, g4.w, b4.w);
    int p = __builtin_amdgcn_cvt_pk_fp8_f32(o0, o1, 0, false);
    p = __builtin_amdgcn_cvt_pk_fp8_f32(o2, o3, p, true);
    hr[pperm(j * 256 + lane * 4) >> 2] = p;
  }
}

// ---- W [K][N] fp32 -> WT [N][K] fp8 e4m3, x16 pre-scale, pi-permuted -----
__global__ __launch_bounds__(256) void transpose_fp8_kernel(
    const float* __restrict__ W, u8* __restrict__ WT) {
  __shared__ float tile[32][33];
  const int tx = threadIdx.x & 31;
  const int ty = threadIdx.x >> 5;
  const int bn = blockIdx.x * 32;
  const int bk = blockIdx.y * 32;
#pragma unroll
  for (int i = 0; i < 32; i += 8)
    tile[ty + i][tx] = W[(size_t)(bk + ty + i) * D_DIM + bn + tx];
  __syncthreads();
#pragma unroll
  for (int i = 0; i < 32; i += 8) {
    const int p =
        __builtin_amdgcn_cvt_pk_fp8_f32(16.f * tile[tx][ty + i], 0.f, 0, false);
    WT[(size_t)(bn + ty + i) * D_DIM + pperm(bk + tx)] = (u8)(p & 0xff);
  }
}

#define VMCNT(n) asm volatile("s_waitcnt vmcnt(" #n ")" ::: "memory")
#define DSRX(d, a, off) \
  asm volatile("ds_read_b128 %0, %1 offset:" #off : "=v"(d) : "v"(a))

// ====== GEMM1: fp8 NT, 128x256 tile, BK=128 mega-steps, ring-3 48KB =======
// c8[M][N] = fp8((h8 x 16*W_in)/16 + bias)
// Buf (48KB): A-plane0 [128r][64B] @0, A-plane1 @8K, B-pl0 [256r][64B] @16K,
// B-pl1 @32K. Each plane = R11's measured-0-conflict 64B-row XOR layout;
// plane c holds K-chunk c (64 bytes) of the 128-byte K-step.
#define NT2 8   // K / 128

__global__ __launch_bounds__(512, 1) void gemm_fp8_big_kernel(
    const u8* __restrict__ A, const u8* __restrict__ BT,
    const float* __restrict__ bias, u8* __restrict__ Cout) {
  __shared__ __attribute__((aligned(16))) char lds[3][49152];
  const int tid  = threadIdx.x;
  const int lane = tid & 63;
  const int wave = tid >> 6;           // 0..7
  const int wr = wave >> 2;            // 0..1 (M half: 64 rows)
  const int wc = wave & 3;             // 0..3 (N quarter: 64 cols)
  const int bid = blockIdx.x;
  const int swz = (bid & 7) * 64 + (bid >> 3);   // 512 blocks, 8 XCDs
  const int m0 = (swz >> 2) * 128;
  const int n0 = (swz & 3) * 256;

  // staging: thread covers (row = tid>>2, phys unit = tid&3) of each plane
  const int us = (((tid & 3) ^ ((tid >> 3) & 3)) << 4);
  const u8* srcA = A  + (size_t)(m0 + (tid >> 2)) * D_DIM + us;
  const u8* srcB = BT + (size_t)(n0 + (tid >> 2)) * D_DIM + us;
  const int l16 = tid * 16;

  const uint32_t lbase = (uint32_t)(uintptr_t)&lds[0][0];
  const int sw = (((lane >> 4) ^ ((lane >> 1) & 3)) << 4);
  const uint32_t aoff = lbase + (uint32_t)((wr * 64 + (lane & 15)) * 64 + sw);
  const uint32_t boff = lbase + 16384u +
                        (uint32_t)((wc * 64 + (lane & 15)) * 64 + sw);

  f32x4 acc[4][4];
#pragma unroll
  for (int m = 0; m < 4; ++m)
#pragma unroll
    for (int n = 0; n < 4; ++n) acc[m][n] = (f32x4){0.f, 0.f, 0.f, 0.f};

  // 6 g2l16 per thread per stage; ko = T*128
#define STAGE(T, BI)                                                   \
  {                                                                    \
    char* dst = (char*)lds + (BI) * 49152;                             \
    const size_t ko = (size_t)(T) * 128;                               \
    g2l16(srcA + ko,       dst + l16);                 /* A plane 0 */ \
    g2l16(srcA + ko + 64,  dst + 8192 + l16);          /* A plane 1 */ \
    g2l16(srcB + ko,       dst + 16384 + l16);         /* B pl0 lo  */ \
    g2l16(srcB + (size_t)128 * D_DIM + ko, dst + 24576 + l16);         \
    g2l16(srcB + ko + 64,  dst + 32768 + l16);         /* B pl1 lo  */ \
    g2l16(srcB + (size_t)128 * D_DIM + ko + 64, dst + 40960 + l16);    \
  }

#define ITER(T)                                                        \
  {                                                                    \
    if ((T) < NT2 - 1) { VMCNT(6); } else { VMCNT(0); }                \
    __builtin_amdgcn_s_barrier();                                      \
    asm volatile("" ::: "memory");                                     \
    const uint32_t bb = (uint32_t)(((T) % 3) * 49152);                 \
    longx2 af0[4], af1[4], bf0[4], bf1[4];                             \
    const uint32_t aA = aoff + bb;                                     \
    const uint32_t bA = boff + bb;                                     \
    DSRX(af0[0], aA, 0);                                               \
    DSRX(af0[1], aA, 1024);                                            \
    DSRX(af0[2], aA, 2048);                                            \
    DSRX(af0[3], aA, 3072);                                            \
    DSRX(af1[0], aA, 8192);                                            \
    DSRX(af1[1], aA, 9216);                                            \
    DSRX(af1[2], aA, 10240);                                           \
    DSRX(af1[3], aA, 11264);                                           \
    DSRX(bf0[0], bA, 0);                                               \
    DSRX(bf0[1], bA, 1024);                                            \
    DSRX(bf0[2], bA, 2048);                                            \
    DSRX(bf0[3], bA, 3072);                                            \
    DSRX(bf1[0], bA, 16384);                                           \
    DSRX(bf1[1], bA, 17408);                                           \
    DSRX(bf1[2], bA, 18432);                                           \
    DSRX(bf1[3], bA, 19456);                                           \
    if ((T) + 2 < NT2) STAGE((T) + 2, ((T) + 2) % 3);                  \
    asm volatile("s_waitcnt lgkmcnt(0)" ::: "memory");                 \
    __builtin_amdgcn_sched_barrier(0);                                 \
    _Pragma("unroll") for (int m = 0; m < 4; ++m)                      \
        _Pragma("unroll") for (int n = 0; n < 4; ++n)                  \
            acc[m][n] = __builtin_amdgcn_mfma_f32_16x16x32_fp8_fp8(    \
                af0[m][0], bf0[n][0], acc[m][n], 0, 0, 0);             \
    _Pragma("unroll") for (int m = 0; m < 4; ++m)                      \
        _Pragma("unroll") for (int n = 0; n < 4; ++n)                  \
            acc[m][n] = __builtin_amdgcn_mfma_f32_16x16x32_fp8_fp8(    \
                af0[m][1], bf0[n][1], acc[m][n], 0, 0, 0);             \
    _Pragma("unroll") for (int m = 0; m < 4; ++m)                      \
        _Pragma("unroll") for (int n = 0; n < 4; ++n)                  \
            acc[m][n] = __builtin_amdgcn_mfma_f32_16x16x32_fp8_fp8(    \
                af1[m][0], bf1[n][0], acc[m][n], 0, 0, 0);             \
    _Pragma("unroll") for (int m = 0; m < 4; ++m)                      \
        _Pragma("unroll") for (int n = 0; n < 4; ++n)                  \
            acc[m][n] = __builtin_amdgcn_mfma_f32_16x16x32_fp8_fp8(    \
                af1[m][1], bf1[n][1], acc[m][n], 0, 0, 0);             \
  }

  STAGE(0, 0);
  STAGE(1, 1);
#pragma unroll
  for (int t = 0; t < NT2; ++t) ITER(t);

#undef ITER
#undef STAGE

  // epilogue: C/D layout col = lane&15, row = (lane>>4)*4 + r; /16 -> fp8
  const int rbase = m0 + wr * 64 + ((lane >> 4) << 2);
  const int cbase = n0 + wc * 64 + (lane & 15);
#pragma unroll
  for (int n = 0; n < 4; ++n) {
    const int col = cbase + n * 16;
    const float bn = bias[col];
#pragma unroll
    for (int m = 0; m < 4; ++m) {
      const int row = rbase + m * 16;
#pragma unroll
      for (int r = 0; r < 4; ++r) {
        const float cv = fmaf(acc[m][n][r], 0.0625f, bn);
        const int p = __builtin_amdgcn_cvt_pk_fp8_f32(cv, 0.f, 0, false);
        Cout[(size_t)(row + r) * D_DIM + col] = (u8)(p & 0xff);
      }
    }
  }
}

// ====== GEMM2 (R11 control): fp8 NT, 128x256, BK=64, ring-3 24KB ==========
// out f32 = xres + (16y x 16W_out)/256 + bias
#define NTK 16        // K / 64
#define BUFSZ 24576

__global__ __launch_bounds__(512, 4) void gemm_fp8_kernel(
    const u8* __restrict__ A, const u8* __restrict__ BT,
    const float* __restrict__ bias, const float* __restrict__ xres,
    float* __restrict__ Cout) {
  __shared__ __attribute__((aligned(16))) char lds[3][BUFSZ];
  const int tid  = threadIdx.x;
  const int lane = tid & 63;
  const int wave = tid >> 6;           // 0..7
  const int wr = wave >> 2;            // 0..1
  const int wc = wave & 3;             // 0..3
  const int bid = blockIdx.x;
  const int swz = (bid & 7) * 64 + (bid >> 3);
  const int m0 = (swz >> 2) * 128;
  const int n0 = (swz & 3) * 256;

  const int dly = (int)((bid * 2654435761u) >> 29);
  for (int i = 0; i < dly; ++i) __builtin_amdgcn_s_sleep(1);

  const int us = (((tid & 3) ^ ((tid >> 3) & 3)) << 4);
  const u8* srcA = A  + (size_t)(m0 + (tid >> 2)) * D_DIM + us;
  const u8* srcB = BT + (size_t)(n0 + (tid >> 2)) * D_DIM + us;
  const int l16 = tid * 16;

  const uint32_t lbase = (uint32_t)(uintptr_t)&lds[0][0];
  const int sw = (((lane >> 4) ^ ((lane >> 1) & 3)) << 4);
  const uint32_t aoff = lbase + (uint32_t)((wr * 64 + (lane & 15)) * 64 + sw);
  const uint32_t boff = lbase + 8192u +
                        (uint32_t)((wc * 64 + (lane & 15)) * 64 + sw);

  f32x4 acc[4][4];
#pragma unroll
  for (int m = 0; m < 4; ++m)
#pragma unroll
    for (int n = 0; n < 4; ++n) acc[m][n] = (f32x4){0.f, 0.f, 0.f, 0.f};

#define STAGE(T, BI)                                           \
  {                                                            \
    char* dst = (char*)lds + (BI) * BUFSZ;                     \
    const size_t ko = (size_t)(T) * 64;                        \
    g2l16(srcA + ko, dst + l16);                               \
    g2l16(srcB + ko, dst + 8192 + l16);                        \
    g2l16(srcB + (size_t)128 * D_DIM + ko, dst + 16384 + l16); \
  }

#define STEP_BODY(CUR, DO_STAGE, T)                                 \
  {                                                                 \
    __builtin_amdgcn_s_barrier();                                   \
    const uint32_t bb = (uint32_t)(CUR) * BUFSZ;                    \
    longx2 af[4], bf[4];                                            \
    const uint32_t aA = aoff + bb;                                  \
    DSRX(af[0], aA, 0);                                             \
    DSRX(af[1], aA, 1024);                                          \
    DSRX(af[2], aA, 2048);                                          \
    DSRX(af[3], aA, 3072);                                          \
    const uint32_t bA = boff + bb;                                  \
    DSRX(bf[0], bA, 0);                                             \
    DSRX(bf[1], bA, 1024);                                          \
    DSRX(bf[2], bA, 2048);                                          \
    DSRX(bf[3], bA, 3072);                                          \
    if (DO_STAGE) { const int bi2 = (CUR) >= 1 ? (CUR) - 1 : (CUR) + 2; \
                    STAGE((T) + 2, bi2); }                          \
    asm volatile("s_waitcnt lgkmcnt(0)" ::: "memory");              \
    __builtin_amdgcn_sched_barrier(0);                              \
    _Pragma("unroll") for (int m = 0; m < 4; ++m)                   \
        _Pragma("unroll") for (int n = 0; n < 4; ++n)               \
            acc[m][n] = __builtin_amdgcn_mfma_f32_16x16x32_fp8_fp8( \
                af[m][0], bf[n][0], acc[m][n], 0, 0, 0);            \
    _Pragma("unroll") for (int m = 0; m < 4; ++m)                   \
        _Pragma("unroll") for (int n = 0; n < 4; ++n)               \
            acc[m][n] = __builtin_amdgcn_mfma_f32_16x16x32_fp8_fp8( \
                af[m][1], bf[n][1], acc[m][n], 0, 0, 0);            \
  }

  STAGE(0, 0);
  STAGE(1, 1);
  int cur = 0;
  for (int t = 0; t < NTK - 1; ++t) {
    VMCNT(3);
    STEP_BODY(cur, t + 2 < NTK, t);
    cur = cur == 2 ? 0 : cur + 1;
  }
  VMCNT(0);
  STEP_BODY(cur, false, NTK - 1);

#undef STEP_BODY
#undef STAGE

  const int rbase = m0 + wr * 64 + ((lane >> 4) << 2);
  const int cbase = n0 + wc * 64 + (lane & 15);
#pragma unroll
  for (int n = 0; n < 4; ++n) {
    const int col = cbase + n * 16;
    const float bn = bias[col];
#pragma unroll
    for (int m = 0; m < 4; ++m) {
      const int row = rbase + m * 16;
#pragma unroll
      for (int r = 0; r < 4; ++r) {
        const size_t idx = (size_t)(row + r) * D_DIM + col;
        Cout[idx] = xres[idx] + fmaf(acc[m][n][r], 1.f / 256.f, bn);
      }
    }
  }
}

// --- chunked chaotic scan: c fp8 linear in, y fp8 x16 pi-permuted out -----
__global__ __launch_bounds__(64) void scan_kernel(
    const u8* __restrict__ c, u8* __restrict__ y) {
  const int b     = blockIdx.y;
  const int chunk = blockIdx.x;
  const int t0    = chunk * CHUNK;
  const int start = (chunk == 0) ? 0 : t0 - WARM;
  const int tend  = t0 + CHUNK;
  const int lane  = threadIdx.x;

  float zre[8], zim[8];
#pragma unroll
  for (int j = 0; j < 8; ++j) { zre[j] = 0.f; zim[j] = 0.f; }

  const int dre = lane * 8;
  const int pre = (dre & ~63) | (((dre >> 3) & 3) << 4) | (((dre >> 5) & 1) << 3);
  const int pim = 512 + pre;

  const u8* crow = c + ((size_t)b * S_DIM + start) * D_DIM;
  u64 cr = *(const u64*)(crow + lane * 8);
  u64 ci = *(const u64*)(crow + 512 + lane * 8);

  for (int t = start; t < tend; ++t) {
    u64 crn = cr, cin = ci;
    if (t + 1 < tend) {
      const u8* nrow = c + ((size_t)b * S_DIM + (t + 1)) * D_DIM;
      crn = *(const u64*)(nrow + lane * 8);
      cin = *(const u64*)(nrow + 512 + lane * 8);
    }
    float cre[8], cim[8];
    {
      const unsigned rl = (unsigned)cr, rh = (unsigned)(cr >> 32);
      const unsigned il = (unsigned)ci, ih = (unsigned)(ci >> 32);
      cre[0] = __builtin_amdgcn_cvt_f32_fp8(rl, 0);
      cre[1] = __builtin_amdgcn_cvt_f32_fp8(rl, 1);
      cre[2] = __builtin_amdgcn_cvt_f32_fp8(rl, 2);
      cre[3] = __builtin_amdgcn_cvt_f32_fp8(rl, 3);
      cre[4] = __builtin_amdgcn_cvt_f32_fp8(rh, 0);
      cre[5] = __builtin_amdgcn_cvt_f32_fp8(rh, 1);
      cre[6] = __builtin_amdgcn_cvt_f32_fp8(rh, 2);
      cre[7] = __builtin_amdgcn_cvt_f32_fp8(rh, 3);
      cim[0] = __builtin_amdgcn_cvt_f32_fp8(il, 0);
      cim[1] = __builtin_amdgcn_cvt_f32_fp8(il, 1);
      cim[2] = __builtin_amdgcn_cvt_f32_fp8(il, 2);
      cim[3] = __builtin_amdgcn_cvt_f32_fp8(il, 3);
      cim[4] = __builtin_amdgcn_cvt_f32_fp8(ih, 0);
      cim[5] = __builtin_amdgcn_cvt_f32_fp8(ih, 1);
      cim[6] = __builtin_amdgcn_cvt_f32_fp8(ih, 2);
      cim[7] = __builtin_amdgcn_cvt_f32_fp8(ih, 3);
    }
    float nr[8], ni[8];
    float ss = 0.f;
#pragma unroll
    for (int j = 0; j < 8; ++j) {
      const float a  = zre[j], bb = zim[j];
      const float rr = fmaf(a, a, fmaf(-bb, bb, cre[j]));
      const float ii = fmaf(2.f * a, bb, cim[j]);
      nr[j] = rr; ni[j] = ii;
      ss = fmaf(rr, rr, ss);
      ss = fmaf(ii, ii, ss);
    }
#pragma unroll
    for (int off = 32; off; off >>= 1) ss += __shfl_xor(ss, off);
    const float nrm = sqrtf(ss + 1e-12f);
    const float sc  = 2.0f / fmaxf(nrm, 2.0f);
#pragma unroll
    for (int j = 0; j < 8; ++j) { zre[j] = nr[j] * sc; zim[j] = ni[j] * sc; }
    if (t >= t0) {
      u8* yrow = y + ((size_t)b * S_DIM + t) * D_DIM;
      int pr0 = __builtin_amdgcn_cvt_pk_fp8_f32(16.f * zre[0], 16.f * zre[1], 0, false);
      pr0 = __builtin_amdgcn_cvt_pk_fp8_f32(16.f * zre[2], 16.f * zre[3], pr0, true);
      int pr1 = __builtin_amdgcn_cvt_pk_fp8_f32(16.f * zre[4], 16.f * zre[5], 0, false);
      pr1 = __builtin_amdgcn_cvt_pk_fp8_f32(16.f * zre[6], 16.f * zre[7], pr1, true);
      int pi0 = __builtin_amdgcn_cvt_pk_fp8_f32(16.f * zim[0], 16.f * zim[1], 0, false);
      pi0 = __builtin_amdgcn_cvt_pk_fp8_f32(16.f * zim[2], 16.f * zim[3], pi0, true);
      int pi1 = __builtin_amdgcn_cvt_pk_fp8_f32(16.f * zim[4], 16.f * zim[5], 0, false);
      pi1 = __builtin_amdgcn_cvt_pk_fp8_f32(16.f * zim[6], 16.f * zim[7], pi1, true);
      *(u64*)(yrow + pre) = ((u64)(unsigned)pr1 << 32) | (unsigned)pr0;
      *(u64*)(yrow + pim) = ((u64)(unsigned)pi1 << 32) | (unsigned)pi0;
    }
    cr = crn; ci = cin;
  }
}

extern "C" void kernel_launch(void* const* d_in, const int* in_sizes, int n_in,
                              void* d_out, int out_size, void* d_ws, size_t ws_size,
                              hipStream_t stream) {
  const float* x     = (const float*)d_in[0];
  const float* gamma = (const float*)d_in[1];
  const float* beta  = (const float*)d_in[2];
  const float* W_in  = (const float*)d_in[3];
  const float* b_in  = (const float*)d_in[4];
  const float* W_out = (const float*)d_in[5];
  const float* b_out = (const float*)d_in[6];
  float* out = (float*)d_out;

  char* ws = (char*)d_ws;
  u8* hy8  = (u8*)(ws);                  // 16 MiB: h fp8, then y fp8 (alias)
  u8* c8   = (u8*)(ws + (16ull << 20));  // 16 MiB: c fp8 (linear)
  u8* wti8 = (u8*)(ws + (64ull << 20));  // 1 MiB:  W_in^T  fp8 (x16, perm)
  u8* wto8 = (u8*)(ws + (65ull << 20));  // 1 MiB:  W_out^T fp8 (x16, perm)

  transpose_fp8_kernel<<<dim3(32, 32), 256, 0, stream>>>(W_in, wti8);
  transpose_fp8_kernel<<<dim3(32, 32), 256, 0, stream>>>(W_out, wto8);
  ln_kernel<<<M_DIM, 64, 0, stream>>>(x, gamma, beta, hy8);
  gemm_fp8_big_kernel<<<512, 512, 0, stream>>>(hy8, wti8, b_in, c8);
  scan_kernel<<<dim3(S_DIM / CHUNK, B_DIM), 64, 0, stream>>>(c8, hy8);
  gemm_fp8_kernel<<<512, 512, 0, stream>>>(hy8, wto8, b_out, x, out);
}

// Round 15
// 111.052 us; speedup vs baseline: 1.4584x; 1.1247x over previous
//
#include <hip/hip_runtime.h>

typedef __bf16 bf16_t;
typedef float  f32x4  __attribute__((ext_vector_type(4)));
typedef int    i32x4  __attribute__((ext_vector_type(4)));
typedef int    i32x8  __attribute__((ext_vector_type(8)));
typedef unsigned char u8;
typedef unsigned long long u64;

#define B_DIM 4
#define S_DIM 4096
#define D_DIM 1024
#define M_DIM (B_DIM * S_DIM)   // 16384 rows

#define CHUNK 32   // scan output steps per block
#define WARM  16   // scan warm-up steps

__device__ __forceinline__ void g2l16(const void* g, void* l) {
  __builtin_amdgcn_global_load_lds(
      (const __attribute__((address_space(1))) void*)g,
      (__attribute__((address_space(3))) void*)l, 16, 0, 0);
}

// ---------------- LayerNorm fp32 -> fp8 e4m3 (linear), wave per row -------
__global__ __launch_bounds__(64) void ln_kernel(
    const float* __restrict__ x, const float* __restrict__ gamma,
    const float* __restrict__ beta, u8* __restrict__ h) {
  const int row  = blockIdx.x;
  const int lane = threadIdx.x;
  const float4* xr = (const float4*)(x + (size_t)row * D_DIM);
  float4 v[4];
  float s = 0.f, s2 = 0.f;
#pragma unroll
  for (int j = 0; j < 4; ++j) {
    v[j] = xr[j * 64 + lane];
    s += v[j].x + v[j].y + v[j].z + v[j].w;
    s2 = fmaf(v[j].x, v[j].x, s2);
    s2 = fmaf(v[j].y, v[j].y, s2);
    s2 = fmaf(v[j].z, v[j].z, s2);
    s2 = fmaf(v[j].w, v[j].w, s2);
  }
#pragma unroll
  for (int off = 32; off; off >>= 1) {
    s  += __shfl_xor(s, off);
    s2 += __shfl_xor(s2, off);
  }
  const float mu  = s * (1.f / (float)D_DIM);
  const float var = fmaf(-mu, mu, s2 * (1.f / (float)D_DIM));
  const float inv = rsqrtf(var + 1e-5f);
  int* hr = (int*)(h + (size_t)row * D_DIM);
#pragma unroll
  for (int j = 0; j < 4; ++j) {
    const float4 g4 = ((const float4*)gamma)[j * 64 + lane];
    const float4 b4 = ((const float4*)beta)[j * 64 + lane];
    const float o0 = fmaf((v[j].x - mu) * inv, g4.x, b4.x);
    const float o1 = fmaf((v[j].y - mu) * inv, g4.y, b4.y);
    const float o2 = fmaf((v[j].z - mu) * inv, g4.z, b4.z);
    const float o3 = fmaf((v[j].w - mu) * inv, g4.w, b4.w);
    int p = __builtin_amdgcn_cvt_pk_fp8_f32(o0, o1, 0, false);
    p = __builtin_amdgcn_cvt_pk_fp8_f32(o2, o3, p, true);
    hr[j * 64 + lane] = p;
  }
}

// ---- W [K][N] fp32 -> WT [N][K] fp8 e4m3 (linear), x16 pre-scale ---------
__global__ __launch_bounds__(256) void transpose_fp8_kernel(
    const float* __restrict__ W, u8* __restrict__ WT) {
  __shared__ float tile[32][33];
  const int tx = threadIdx.x & 31;
  const int ty = threadIdx.x >> 5;
  const int bn = blockIdx.x * 32;
  const int bk = blockIdx.y * 32;
#pragma unroll
  for (int i = 0; i < 32; i += 8)
    tile[ty + i][tx] = W[(size_t)(bk + ty + i) * D_DIM + bn + tx];
  __syncthreads();
#pragma unroll
  for (int i = 0; i < 32; i += 8) {
    const int p =
        __builtin_amdgcn_cvt_pk_fp8_f32(16.f * tile[tx][ty + i], 0.f, 0, false);
    WT[(size_t)(bn + ty + i) * D_DIM + bk + tx] = (u8)(p & 0xff);
  }
}

// ====== MX-fp8 NT GEMM: 128x128 tile, 4 waves, BK=128, K=128 MFMA =========
// MODE 0 (GEMM1): h8 x (16*W_in)  -> c8 = fp8(acc/16 + bias)
// MODE 1 (GEMM2): (16*y8) x (16*W_out) -> f32 out = xres + acc/256 + bias
// mfma_scale_f32_16x16x128_f8f6f4, both scales E8M0 127 (=1.0) -> numerics
// identical to fp8_fp8. Lane fragment: row = lane&15, k-bytes
// [(lane>>4)*32, +32) = LDS units 2g, 2g+1 of the 128B row-chunk.
// LDS region [128 rows][128B]: unit u stored at phys p = u ^ (row&7)
// (8 units/row; balanced 8-accesses/bank = b128 floor).
#define NMX 8   // K / 128

__device__ __forceinline__ i32x8 ldfrag(const char* region, int row, int g) {
  const int x = row & 7;
  const i32x4 lo =
      *(const i32x4*)(region + row * 128 + ((((g << 1)) ^ x) << 4));
  const i32x4 hi =
      *(const i32x4*)(region + row * 128 + ((((g << 1) | 1) ^ x) << 4));
  i32x8 r;
  r[0] = lo[0]; r[1] = lo[1]; r[2] = lo[2]; r[3] = lo[3];
  r[4] = hi[0]; r[5] = hi[1]; r[6] = hi[2]; r[7] = hi[3];
  return r;
}

template <int MODE>
__global__ __launch_bounds__(256, 2) void gemm_mx_kernel(
    const u8* __restrict__ A, const u8* __restrict__ BT,
    const float* __restrict__ bias, const float* __restrict__ xres,
    void* __restrict__ Cout) {
  __shared__ __attribute__((aligned(16))) char lds[2][32768];
  const int tid  = threadIdx.x;
  const int lane = tid & 63;
  const int wave = tid >> 6;          // 0..3
  const int wr = wave >> 1;           // 0..1 (M half: 64 rows)
  const int wc = wave & 1;            // 0..1 (N half: 64 cols)
  const int bid = blockIdx.x;
  const int swz = (bid & 7) * 128 + (bid >> 3);  // 1024 blocks, 8 XCDs
  const int m0 = (swz >> 3) * 128;    // 128 m-panels
  const int n0 = (swz & 7) * 128;     // 8 n-panels

  // staging: dest unit i = tid + j*256 -> (row = i>>3, phys p = i&7);
  // source unit u = p ^ (row&7); row&7 invariant across j (stride 32 rows)
  const int srow = tid >> 3;          // 0..31
  const int us   = (((tid & 7) ^ (srow & 7)) << 4);
  const u8* srcA = A  + (size_t)(m0 + srow) * D_DIM + us;
  const u8* srcB = BT + (size_t)(n0 + srow) * D_DIM + us;
  const int dst0 = tid * 16;

  const int frow = lane & 15;
  const int g    = lane >> 4;

  f32x4 acc[4][4];
#pragma unroll
  for (int m = 0; m < 4; ++m)
#pragma unroll
    for (int n = 0; n < 4; ++n) acc[m][n] = (f32x4){0.f, 0.f, 0.f, 0.f};

#define STAGE(T)                                             \
  {                                                          \
    char* dst = lds[(T) & 1];                                \
    const size_t ko = (size_t)(T) * 128;                     \
    g2l16(srcA + ko,                          dst + dst0);   \
    g2l16(srcA + (size_t)32 * D_DIM + ko, dst + 4096 + dst0);  \
    g2l16(srcA + (size_t)64 * D_DIM + ko, dst + 8192 + dst0);  \
    g2l16(srcA + (size_t)96 * D_DIM + ko, dst + 12288 + dst0); \
    g2l16(srcB + ko,                      dst + 16384 + dst0); \
    g2l16(srcB + (size_t)32 * D_DIM + ko, dst + 20480 + dst0); \
    g2l16(srcB + (size_t)64 * D_DIM + ko, dst + 24576 + dst0); \
    g2l16(srcB + (size_t)96 * D_DIM + ko, dst + 28672 + dst0); \
  }

  STAGE(0);
  for (int t = 0; t < NMX; ++t) {
    __syncthreads();   // stage(t) DMA drained; prev readers of buf done
    const char* buf = lds[t & 1];
    i32x8 af[4], bf[4];
#pragma unroll
    for (int m = 0; m < 4; ++m)
      af[m] = ldfrag(buf, wr * 64 + m * 16 + frow, g);
#pragma unroll
    for (int n = 0; n < 4; ++n)
      bf[n] = ldfrag(buf + 16384, wc * 64 + n * 16 + frow, g);
    if (t + 1 < NMX) STAGE(t + 1);
#pragma unroll
    for (int m = 0; m < 4; ++m)
#pragma unroll
      for (int n = 0; n < 4; ++n)
        acc[m][n] = __builtin_amdgcn_mfma_scale_f32_16x16x128_f8f6f4(
            af[m], bf[n], acc[m][n], 0, 0,
            0, 0x7f7f7f7f, 0, 0x7f7f7f7f);   // E8M0 127 = 1.0 (all bytes)
  }
#undef STAGE

  // epilogue: C/D layout col = lane&15, row = (lane>>4)*4 + r
  const int rbase = m0 + wr * 64 + ((lane >> 4) << 2);
  const int cbase = n0 + wc * 64 + (lane & 15);
#pragma unroll
  for (int n = 0; n < 4; ++n) {
    const int col = cbase + n * 16;
    const float bn = bias[col];
#pragma unroll
    for (int m = 0; m < 4; ++m) {
      const int row = rbase + m * 16;
#pragma unroll
      for (int r = 0; r < 4; ++r) {
        const size_t idx = (size_t)(row + r) * D_DIM + col;
        if (MODE == 0) {
          const float cv = fmaf(acc[m][n][r], 0.0625f, bn);
          const int p = __builtin_amdgcn_cvt_pk_fp8_f32(cv, 0.f, 0, false);
          ((u8*)Cout)[idx] = (u8)(p & 0xff);
        } else {
          ((float*)Cout)[idx] =
              xres[idx] + fmaf(acc[m][n][r], 1.f / 256.f, bn);
        }
      }
    }
  }
}

// --- chunked chaotic scan: c fp8 linear in, y fp8 x16 linear out ----------
__global__ __launch_bounds__(64) void scan_kernel(
    const u8* __restrict__ c, u8* __restrict__ y) {
  const int b     = blockIdx.y;
  const int chunk = blockIdx.x;
  const int t0    = chunk * CHUNK;
  const int start = (chunk == 0) ? 0 : t0 - WARM;
  const int tend  = t0 + CHUNK;
  const int lane  = threadIdx.x;

  float zre[8], zim[8];
#pragma unroll
  for (int j = 0; j < 8; ++j) { zre[j] = 0.f; zim[j] = 0.f; }

  const u8* crow = c + ((size_t)b * S_DIM + start) * D_DIM;
  u64 cr = *(const u64*)(crow + lane * 8);
  u64 ci = *(const u64*)(crow + 512 + lane * 8);

  for (int t = start; t < tend; ++t) {
    u64 crn = cr, cin = ci;
    if (t + 1 < tend) {
      const u8* nrow = c + ((size_t)b * S_DIM + (t + 1)) * D_DIM;
      crn = *(const u64*)(nrow + lane * 8);
      cin = *(const u64*)(nrow + 512 + lane * 8);
    }
    float cre[8], cim[8];
    {
      const unsigned rl = (unsigned)cr, rh = (unsigned)(cr >> 32);
      const unsigned il = (unsigned)ci, ih = (unsigned)(ci >> 32);
      cre[0] = __builtin_amdgcn_cvt_f32_fp8(rl, 0);
      cre[1] = __builtin_amdgcn_cvt_f32_fp8(rl, 1);
      cre[2] = __builtin_amdgcn_cvt_f32_fp8(rl, 2);
      cre[3] = __builtin_amdgcn_cvt_f32_fp8(rl, 3);
      cre[4] = __builtin_amdgcn_cvt_f32_fp8(rh, 0);
      cre[5] = __builtin_amdgcn_cvt_f32_fp8(rh, 1);
      cre[6] = __builtin_amdgcn_cvt_f32_fp8(rh, 2);
      cre[7] = __builtin_amdgcn_cvt_f32_fp8(rh, 3);
      cim[0] = __builtin_amdgcn_cvt_f32_fp8(il, 0);
      cim[1] = __builtin_amdgcn_cvt_f32_fp8(il, 1);
      cim[2] = __builtin_amdgcn_cvt_f32_fp8(il, 2);
      cim[3] = __builtin_amdgcn_cvt_f32_fp8(il, 3);
      cim[4] = __builtin_amdgcn_cvt_f32_fp8(ih, 0);
      cim[5] = __builtin_amdgcn_cvt_f32_fp8(ih, 1);
      cim[6] = __builtin_amdgcn_cvt_f32_fp8(ih, 2);
      cim[7] = __builtin_amdgcn_cvt_f32_fp8(ih, 3);
    }
    float nr[8], ni[8];
    float ss = 0.f;
#pragma unroll
    for (int j = 0; j < 8; ++j) {
      const float a  = zre[j], bb = zim[j];
      const float rr = fmaf(a, a, fmaf(-bb, bb, cre[j]));
      const float ii = fmaf(2.f * a, bb, cim[j]);
      nr[j] = rr; ni[j] = ii;
      ss = fmaf(rr, rr, ss);
      ss = fmaf(ii, ii, ss);
    }
#pragma unroll
    for (int off = 32; off; off >>= 1) ss += __shfl_xor(ss, off);
    const float nrm = sqrtf(ss + 1e-12f);
    const float sc  = 2.0f / fmaxf(nrm, 2.0f);
#pragma unroll
    for (int j = 0; j < 8; ++j) { zre[j] = nr[j] * sc; zim[j] = ni[j] * sc; }
    if (t >= t0) {
      u8* yrow = y + ((size_t)b * S_DIM + t) * D_DIM;
      int pr0 = __builtin_amdgcn_cvt_pk_fp8_f32(16.f * zre[0], 16.f * zre[1], 0, false);
      pr0 = __builtin_amdgcn_cvt_pk_fp8_f32(16.f * zre[2], 16.f * zre[3], pr0, true);
      int pr1 = __builtin_amdgcn_cvt_pk_fp8_f32(16.f * zre[4], 16.f * zre[5], 0, false);
      pr1 = __builtin_amdgcn_cvt_pk_fp8_f32(16.f * zre[6], 16.f * zre[7], pr1, true);
      int pi0 = __builtin_amdgcn_cvt_pk_fp8_f32(16.f * zim[0], 16.f * zim[1], 0, false);
      pi0 = __builtin_amdgcn_cvt_pk_fp8_f32(16.f * zim[2], 16.f * zim[3], pi0, true);
      int pi1 = __builtin_amdgcn_cvt_pk_fp8_f32(16.f * zim[4], 16.f * zim[5], 0, false);
      pi1 = __builtin_amdgcn_cvt_pk_fp8_f32(16.f * zim[6], 16.f * zim[7], pi1, true);
      *(u64*)(yrow + lane * 8)       = ((u64)(unsigned)pr1 << 32) | (unsigned)pr0;
      *(u64*)(yrow + 512 + lane * 8) = ((u64)(unsigned)pi1 << 32) | (unsigned)pi0;
    }
    cr = crn; ci = cin;
  }
}

extern "C" void kernel_launch(void* const* d_in, const int* in_sizes, int n_in,
                              void* d_out, int out_size, void* d_ws, size_t ws_size,
                              hipStream_t stream) {
  const float* x     = (const float*)d_in[0];
  const float* gamma = (const float*)d_in[1];
  const float* beta  = (const float*)d_in[2];
  const float* W_in  = (const float*)d_in[3];
  const float* b_in  = (const float*)d_in[4];
  const float* W_out = (const float*)d_in[5];
  const float* b_out = (const float*)d_in[6];
  float* out = (float*)d_out;

  char* ws = (char*)d_ws;
  u8* hy8  = (u8*)(ws);                  // 16 MiB: h fp8, then y fp8 (alias)
  u8* c8   = (u8*)(ws + (16ull << 20));  // 16 MiB: c fp8
  u8* wti8 = (u8*)(ws + (64ull << 20));  // 1 MiB:  W_in^T  fp8 (x16)
  u8* wto8 = (u8*)(ws + (65ull << 20));  // 1 MiB:  W_out^T fp8 (x16)

  transpose_fp8_kernel<<<dim3(32, 32), 256, 0, stream>>>(W_in, wti8);
  transpose_fp8_kernel<<<dim3(32, 32), 256, 0, stream>>>(W_out, wto8);
  ln_kernel<<<M_DIM, 64, 0, stream>>>(x, gamma, beta, hy8);
  gemm_mx_kernel<0><<<1024, 256, 0, stream>>>(hy8, wti8, b_in, nullptr, c8);
  scan_kernel<<<dim3(S_DIM / CHUNK, B_DIM), 64, 0, stream>>>(c8, hy8);
  gemm_mx_kernel<1><<<1024, 256, 0, stream>>>(hy8, wto8, b_out, x, out);
}